// Round 1
// baseline (602.046 us; speedup 1.0000x reference)
//
#include <hip/hip_runtime.h>
#include <math.h>

#define N_PTS   1000000
#define CI      10
#define C       64
#define NSEG    30000
#define BN_EPS  1e-3f

// ws layout (floats):
// [0:64)    sum_x        (accumulator, zeroed)
// [64:128)  sum_x2       (accumulator, zeroed)
// [128:192) a = rstd*gamma
// [192:256) b = beta - mu*a
// [256:320) g_sum        (accumulator, zeroed)
// [320:384) xg

// Pass 1: per-channel sum and sum-of-squares of x = inputs @ W^T.
// One wave per point-stride; lane = channel; inputs broadcast within wave.
__global__ void __launch_bounds__(256) k_stats(const float* __restrict__ inp,
                                               const float* __restrict__ W,
                                               float* __restrict__ ws) {
    const int lane = threadIdx.x & 63;
    const int wid  = (blockIdx.x * blockDim.x + threadIdx.x) >> 6;
    const int nw   = (gridDim.x * blockDim.x) >> 6;

    float w[CI];
#pragma unroll
    for (int i = 0; i < CI; ++i) w[i] = W[lane * CI + i];

    float s = 0.f, s2 = 0.f;
    for (int p = wid; p < N_PTS; p += nw) {
        const float* row = inp + (size_t)p * CI;
        float v = 0.f;
#pragma unroll
        for (int i = 0; i < CI; ++i) v = fmaf(w[i], row[i], v);
        s += v;
        s2 = fmaf(v, v, s2);
    }

    __shared__ float ls[256], ls2[256];
    ls[threadIdx.x] = s; ls2[threadIdx.x] = s2;
    __syncthreads();
    if (threadIdx.x < 64) {
        float ts = 0.f, ts2 = 0.f;
#pragma unroll
        for (int q = 0; q < 4; ++q) { ts += ls[q * 64 + threadIdx.x]; ts2 += ls2[q * 64 + threadIdx.x]; }
        atomicAdd(&ws[threadIdx.x], ts);
        atomicAdd(&ws[64 + threadIdx.x], ts2);
    }
}

// Finalize BN: a = rstd*gamma, b = beta - mu*a
__global__ void k_finalize(const float* __restrict__ gamma,
                           const float* __restrict__ beta,
                           float* __restrict__ ws) {
    const int c = threadIdx.x;
    const float inv_n = 1.f / (float)N_PTS;
    float mu  = ws[c] * inv_n;
    float var = ws[64 + c] * inv_n - mu * mu;
    float rstd = rsqrtf(var + BN_EPS);
    float a = rstd * gamma[c];
    ws[128 + c] = a;
    ws[192 + c] = beta[c] - mu * a;
}

// Pass 2: per-channel sum of xn = relu(a*x + b)  (for global branch mean g)
__global__ void __launch_bounds__(256) k_gstats(const float* __restrict__ inp,
                                                const float* __restrict__ W,
                                                float* __restrict__ ws) {
    const int lane = threadIdx.x & 63;
    const int wid  = (blockIdx.x * blockDim.x + threadIdx.x) >> 6;
    const int nw   = (gridDim.x * blockDim.x) >> 6;

    float w[CI];
#pragma unroll
    for (int i = 0; i < CI; ++i) w[i] = W[lane * CI + i];
    const float a = ws[128 + lane];
    const float b = ws[192 + lane];

    float s = 0.f;
    for (int p = wid; p < N_PTS; p += nw) {
        const float* row = inp + (size_t)p * CI;
        float v = 0.f;
#pragma unroll
        for (int i = 0; i < CI; ++i) v = fmaf(w[i], row[i], v);
        s += fmaxf(fmaf(v, a, b), 0.f);
    }

    __shared__ float ls[256];
    ls[threadIdx.x] = s;
    __syncthreads();
    if (threadIdx.x < 64) {
        float ts = 0.f;
#pragma unroll
        for (int q = 0; q < 4; ++q) ts += ls[q * 64 + threadIdx.x];
        atomicAdd(&ws[256 + threadIdx.x], ts);
    }
}

// Finalize global branch: xg = pw2 @ relu(dw2 * g)
__global__ void k_xg(const float* __restrict__ dw2,
                     const float* __restrict__ pw2,
                     float* __restrict__ ws) {
    __shared__ float t[C];
    const int c = threadIdx.x;
    float g = ws[256 + c] * (1.f / (float)N_PTS);
    t[c] = fmaxf(dw2[c] * g, 0.f);
    __syncthreads();
    float acc = 0.f;
#pragma unroll
    for (int k = 0; k < C; ++k) acc = fmaf(pw2[c * C + k], t[k], acc);
    ws[320 + c] = acc;
}

// Pass 3: one wave (== one 64-thread block) per segment; lane = channel.
// Recompute x, BN+ReLU, swish, 64x64 matvec via LDS broadcast + pw1 rows in
// VGPRs, sigmoid gate, then sequential per-lane segment sum/max. No atomics;
// coalesced output write.
__global__ void __launch_bounds__(64) k_main(const float* __restrict__ inp,
                                             const int* __restrict__ idx,
                                             const float* __restrict__ W,
                                             const float* __restrict__ dw1,
                                             const float* __restrict__ pw1,
                                             const float* __restrict__ ws,
                                             float* __restrict__ out) {
    const int s    = blockIdx.x;
    const int lane = threadIdx.x;

    float w[CI];
#pragma unroll
    for (int i = 0; i < CI; ++i) w[i] = W[lane * CI + i];

    float pr[C];
#pragma unroll
    for (int k = 0; k < C; k += 4) {
        const float4 v = *(const float4*)(pw1 + lane * C + k);
        pr[k] = v.x; pr[k + 1] = v.y; pr[k + 2] = v.z; pr[k + 3] = v.w;
    }

    const float a   = ws[128 + lane];
    const float b   = ws[192 + lane];
    const float d1  = dw1[lane];
    const float xgc = ws[320 + lane];

    // Binary search for segment bounds in sorted unq_inv (uniform across wave).
    int lo = 0, hi = N_PTS;
    while (lo < hi) { int m = (lo + hi) >> 1; if (idx[m] < s) lo = m + 1; else hi = m; }
    const int start = lo;
    hi = N_PTS;
    while (lo < hi) { int m = (lo + hi) >> 1; if (idx[m] < s + 1) lo = m + 1; else hi = m; }
    const int end = lo;

    __shared__ float sw_lds[C];

    float sm = 0.f, mx = -INFINITY;
    for (int p = start; p < end; ++p) {
        const float* row = inp + (size_t)p * CI;
        float v = 0.f;
#pragma unroll
        for (int i = 0; i < CI; ++i) v = fmaf(w[i], row[i], v);
        float xn = fmaxf(fmaf(v, a, b), 0.f);            // BN + ReLU
        float s1 = xn * d1;
        float swish = s1 / (1.f + __expf(-s1));          // s * sigmoid(s)

        __syncthreads();                                  // single-wave block: cheap
        sw_lds[lane] = swish;
        __syncthreads();

        float xl = 0.f;
        const float4* swv = (const float4*)sw_lds;
#pragma unroll
        for (int k4 = 0; k4 < C / 4; ++k4) {
            float4 vv = swv[k4];
            xl = fmaf(pr[4 * k4 + 0], vv.x, xl);
            xl = fmaf(pr[4 * k4 + 1], vv.y, xl);
            xl = fmaf(pr[4 * k4 + 2], vv.z, xl);
            xl = fmaf(pr[4 * k4 + 3], vv.w, xl);
        }

        float wei = 1.f / (1.f + __expf(-(xl + xgc)));   // sigmoid
        float xi  = xn * (1.f + wei);
        sm += xi;
        mx = fmaxf(mx, xi);
    }

    out[(size_t)s * C + lane] = mx + sm;
}

extern "C" void kernel_launch(void* const* d_in, const int* in_sizes, int n_in,
                              void* d_out, int out_size, void* d_ws, size_t ws_size,
                              hipStream_t stream) {
    const float* inp   = (const float*)d_in[0];
    const int*   unq   = (const int*)d_in[1];
    const float* W     = (const float*)d_in[2];
    const float* gamma = (const float*)d_in[3];
    const float* beta  = (const float*)d_in[4];
    const float* dw1   = (const float*)d_in[5];
    const float* pw1   = (const float*)d_in[6];
    const float* dw2   = (const float*)d_in[7];
    const float* pw2   = (const float*)d_in[8];
    float* out = (float*)d_out;
    float* ws  = (float*)d_ws;

    hipMemsetAsync(ws, 0, 384 * sizeof(float), stream);   // zero accumulators (ws is poisoned)

    k_stats   <<<512, 256, 0, stream>>>(inp, W, ws);
    k_finalize<<<1,   64,  0, stream>>>(gamma, beta, ws);
    k_gstats  <<<512, 256, 0, stream>>>(inp, W, ws);
    k_xg      <<<1,   64,  0, stream>>>(dw2, pw2, ws);
    k_main    <<<NSEG, 64, 0, stream>>>(inp, unq, W, dw1, pw1, ws, out);
}